// Round 11
// baseline (411.063 us; speedup 1.0000x reference)
//
#include <hip/hip_runtime.h>
#include <stdint.h>

#define NREG   20
#define EDIM   768
#define DVOL   64
#define HVOL   512
#define WVOL   512
#define HW_    (HVOL * WVOL)
#define DHW_   (DVOL * HVOL * WVOL)
#define NPATCH 16384
#define BTOT   2
#define PROTO_N (NREG * EDIM)            // 15360
#define RF_N    (BTOT * PROTO_N)         // 30720 floats (output 0)
#define TOTAL_PATCHES (BTOT * NPATCH)    // 32768
#define NBUCKET 1024                     // 2 b x 32 zbins x 16 ybins

#define PROD_BLOCKS 512                  // compact producers (dispatched first)
#define CONS_BLOCKS 8192                 // assign consumers
#define FUSED_BLOCKS (PROD_BLOCKS + CONS_BLOCKS)

// ---- workspace layout ------------------------------------------------------
// [0, 33.5MB): int8 compact mask; 64B pad; 512 region flags; sort arrays.
#define SEG8_BYTES  (BTOT * DHW_)                  // 33,554,432
#define W_DONE      ((SEG8_BYTES / 4) + 16)        // 512 flags
#define W_COUNTS    (W_DONE + 512)                 // 1024
#define W_OFFS      (W_COUNTS + NBUCKET)           // 1024
#define W_KEYS      (W_OFFS + NBUCKET)             // 32768
#define W_PID       (W_KEYS + TOTAL_PATCHES)
#define W_C0        (W_PID  + TOTAL_PATCHES)
#define W_C1        (W_C0   + TOTAL_PATCHES)
#define W_C2        (W_C1   + TOTAL_PATCHES)

__device__ __forceinline__ uint32_t pack4i(int4 v)
{
    return (uint32_t)v.x | ((uint32_t)v.y << 8)
         | ((uint32_t)v.z << 16) | ((uint32_t)v.w << 24);
}

// ---------------------------------------------------------------------------
// Sort pass 1: keys + bucket counts (+ proto broadcast).
// ---------------------------------------------------------------------------
__global__ __launch_bounds__(256) void count_kernel(
    const float* __restrict__ coords,
    const float* __restrict__ proto,
    float*       __restrict__ out,
    unsigned*    __restrict__ ws)
{
    const int p = (int)blockIdx.x * 256 + (int)threadIdx.x;
    if (p < RF_N) out[p] = proto[p >= PROTO_N ? p - PROTO_N : p];

    const int b = p >> 14;
    const int zbin = ((int)(coords[p * 3 + 0] * 64.0f))  >> 1;  // 0..31
    const int ybin = ((int)(coords[p * 3 + 1] * 512.0f)) >> 5;  // 0..15
    const unsigned key = (unsigned)(b * 512 + zbin * 16 + ybin);
    ws[W_KEYS + p] = key;
    atomicAdd(&ws[W_COUNTS + key], 1u);
}

// ---------------------------------------------------------------------------
// Sort pass 2: exclusive prefix over 1024 buckets; also zero region flags.
// ---------------------------------------------------------------------------
__global__ __launch_bounds__(1024) void scan_kernel(unsigned* __restrict__ ws)
{
    __shared__ unsigned tmp[NBUCKET];
    const int t = threadIdx.x;
    if (t < 512) ws[W_DONE + t] = 0u;             // zero producer flags
    const unsigned v = ws[W_COUNTS + t];
    tmp[t] = v;
    __syncthreads();
#pragma unroll
    for (int off = 1; off < NBUCKET; off <<= 1) {
        const unsigned y = (t >= off) ? tmp[t - off] : 0u;
        __syncthreads();
        tmp[t] += y;
        __syncthreads();
    }
    ws[W_OFFS + t] = tmp[t] - v;                  // exclusive prefix
}

// ---------------------------------------------------------------------------
// Sort pass 3: scatter pid + SoA coords into globally sorted order.
// ---------------------------------------------------------------------------
__global__ __launch_bounds__(256) void scatter_kernel(
    const float* __restrict__ coords, unsigned* __restrict__ ws)
{
    const int p = (int)blockIdx.x * 256 + (int)threadIdx.x;
    const unsigned key  = ws[W_KEYS + p];
    const unsigned rank = atomicAdd(&ws[W_OFFS + key], 1u);
    ws[W_PID + rank] = (unsigned)p;
    ((float*)ws)[W_C0 + rank] = coords[p * 3 + 0];
    ((float*)ws)[W_C1 + rank] = coords[p * 3 + 1];
    ((float*)ws)[W_C2 + rank] = coords[p * 3 + 2];
}

// ---------------------------------------------------------------------------
// Fused producer/consumer kernel.
//  blocks [0,512): compact int32->int8, one 65536-voxel region each,
//    region order round-robin across the 8 (b, z-quartile) classes so all
//    consumer classes' data lands proportionally; release-flag per region.
//  blocks [512,8704): one wave per sorted slot; byte-window histogram.
//    Bounded spin on per-row region flags; int32 fallback on timeout ->
//    correct under ANY scheduler (no deadlock possible).
// ---------------------------------------------------------------------------
__global__ __launch_bounds__(256) void fused_kernel(
    const int*   __restrict__ seg,
    unsigned*    __restrict__ wsw,
    float*       __restrict__ out)
{
    uint8_t* seg8 = (uint8_t*)wsw;
    float*   wsf  = (float*)wsw;
    const int bid = (int)blockIdx.x;
    const int tid = (int)threadIdx.x;

    if (bid < PROD_BLOCKS) {
        // ---------------- producer: compact one 64K-voxel region -----------
        const unsigned grp = (unsigned)bid & 7u;         // (b, z-quartile)
        const unsigned idx = (unsigned)bid >> 3;         // 0..63
        const unsigned region = (grp >> 2) * 256u + (grp & 3u) * 64u + idx;
        const size_t base = (size_t)region << 16;        // int offset

#pragma unroll
        for (int it = 0; it < 16; ++it) {
            const size_t o = base + (size_t)it * 4096 + (size_t)tid * 16;
            const int4* ip = (const int4*)(seg + o);
            const int4 v0 = ip[0], v1 = ip[1], v2 = ip[2], v3 = ip[3];
            uint4 w;
            w.x = pack4i(v0); w.y = pack4i(v1);
            w.z = pack4i(v2); w.w = pack4i(v3);
            *(uint4*)(seg8 + o) = w;
        }
        __threadfence();
        __syncthreads();
        if (tid == 0)
            __hip_atomic_store(&wsw[W_DONE + region], 1u,
                               __ATOMIC_RELEASE, __HIP_MEMORY_SCOPE_AGENT);
        return;
    }

    // ---------------- consumer: one wave per sorted slot --------------------
    const int cbid = bid - PROD_BLOCKS;
    const int cls  = cbid & 7;                // XCD class -> sorted 1/8 range
    const int pos  = cbid >> 3;               // 0..1023 within class
    const int lane = tid & 63;
    const int wave = tid >> 6;
    const int slot = cls * 4096 + pos * 4 + wave;

    const int   patch = (int)wsw[W_PID + slot];
    const float c0 = wsf[W_C0 + slot] * 64.0f;    // z
    const float c1 = wsf[W_C1 + slot] * 512.0f;   // y
    const float c2 = wsf[W_C2 + slot] * 512.0f;   // x
    const int b = patch >> 14;

    const int sz = (int)fmaxf(0.0f,   floorf(c0 - 2.0f));
    const int ez = (int)fminf(64.0f,  floorf(c0 + 2.0f));
    const int sy = (int)fmaxf(0.0f,   floorf(c1 - 8.0f));
    const int ey = (int)fminf(512.0f, floorf(c1 + 8.0f));
    const int sx = (int)fmaxf(0.0f,   floorf(c2 - 8.0f));
    const int ex = (int)fminf(512.0f, floorf(c2 + 8.0f));

    const int zz = lane >> 4;                 // 0..3
    const int yy = lane & 15;                 // 0..15
    const int zi = sz + zz;
    const int yi = sy + yy;
    const int ziC = min(zi, DVOL - 1);
    const int yiC = min(yi, HVOL - 1);
    const int a0  = sx & ~7;                  // 8B-aligned window base
    const int sh  = (sx & 7) * 8;
    const int rowoff = b * DHW_ + ziC * HW_ + yiC * WVOL;

    // ---- wait for this row's producer region (bounded; fallback on timeout)
    const int need = ((zi < ez) & (yi < ey)) ? 1 : 0;
    const int fid  = rowoff >> 16;
    unsigned ok = need ? 0u : 1u;
    for (int it = 0; it < 4096; ++it) {
        if (!ok) ok = __hip_atomic_load(&wsw[W_DONE + fid],
                        __ATOMIC_ACQUIRE, __HIP_MEMORY_SCOPE_AGENT);
        if (__all((int)ok)) break;
        __builtin_amdgcn_s_sleep(4);
    }
    const int use32 = need && !ok;            // ~never taken

    // ---- byte-window loads (garbage safe: masked or fallback) -------------
    const uint8_t* rp = seg8 + (size_t)rowoff + a0;
    const uint64_t u0 = *(const uint64_t*)(rp);
    const uint64_t u1 = *(const uint64_t*)(rp + 8);
    const uint64_t u2 = *(const uint64_t*)(rp + 16);

    uint64_t A  = (u0 >> sh) | (sh ? (u1 << (64 - sh)) : 0ull);
    uint64_t Bv = (u1 >> sh) | (sh ? (u2 << (64 - sh)) : 0ull);

    const int nv  = min(max(ex - sx, 0), 16);
    const int nvB = max(nv - 8, 0);
    uint64_t mA = (nv  >= 8) ? ~0ull : ((1ull << (8 * nv )) - 1ull);
    uint64_t mB = (nvB >= 8) ? ~0ull : ((1ull << (8 * nvB)) - 1ull);
    if (!need || use32) { mA = 0ull; mB = 0ull; }
    A &= mA;  Bv &= mB;

    // ---- packed 8-bit histogram: cc[k] holds regions 4k..4k+3 -------------
    unsigned cc[5] = {0u, 0u, 0u, 0u, 0u};
    const uint32_t wd[4] = {(uint32_t)A,  (uint32_t)(A  >> 32),
                            (uint32_t)Bv, (uint32_t)(Bv >> 32)};
#pragma unroll
    for (int d = 0; d < 4; ++d) {
        const uint32_t x = wd[d];
#pragma unroll
        for (int j = 0; j < 4; ++j) {
            const int v = (int)((x >> (8 * j)) & 0xFFu);
            const int t = v - 1;                       // -1 if not counted
            const unsigned inc = 1u << ((t & 3) << 3);
            const int qk = t >> 2;                     // -1 matches no k
#pragma unroll
            for (int k = 0; k < 5; ++k)
                cc[k] += (qk == k) ? inc : 0u;
        }
    }

    // ---- int32 fallback (correctness safety net; dead in practice) --------
    if (use32) {
        const int* rp32 = seg + rowoff;
        for (int j = 0; j < 16; ++j) {
            const int p = sx + j;
            const int v = (p < ex) ? rp32[min(p, WVOL - 1)] : 0;
            const int t = v - 1;
            const unsigned inc = 1u << ((t & 3) << 3);
            const int qk = t >> 2;
#pragma unroll
            for (int k = 0; k < 5; ++k)
                cc[k] += (qk == k) ? inc : 0u;
        }
    }

    // ---- 3-step packed butterfly (8-lane groups; per-lane max 16) ---------
#pragma unroll
    for (int off = 1; off < 8; off <<= 1) {
#pragma unroll
        for (int k = 0; k < 5; ++k)
            cc[k] += (unsigned)__shfl_xor((int)cc[k], off);
    }

    // unpack 8-bit -> 2x16-bit, 3 more steps across the 8 groups
    unsigned lo[5], hi[5];
#pragma unroll
    for (int k = 0; k < 5; ++k) {
        lo[k] = cc[k] & 0x00FF00FFu;          // regions 4k (lo16), 4k+2 (hi16)
        hi[k] = (cc[k] >> 8) & 0x00FF00FFu;   // regions 4k+1,      4k+3
    }
#pragma unroll
    for (int off = 8; off < 64; off <<= 1) {
#pragma unroll
        for (int k = 0; k < 5; ++k) {
            lo[k] += (unsigned)__shfl_xor((int)lo[k], off);
            hi[k] += (unsigned)__shfl_xor((int)hi[k], off);
        }
    }

    unsigned S = 0u;
#pragma unroll
    for (int k = 0; k < 5; ++k) S += lo[k] + hi[k];
    const unsigned tot = (S & 0xFFFFu) + (S >> 16);   // <= 1024, no carry

    const int r = lane & 3;
    const unsigned sLo = (lane < 4) ? lo[0] : (lane < 8) ? lo[1]
                       : (lane < 12) ? lo[2] : (lane < 16) ? lo[3] : lo[4];
    const unsigned sHi = (lane < 4) ? hi[0] : (lane < 8) ? hi[1]
                       : (lane < 12) ? hi[2] : (lane < 16) ? hi[3] : hi[4];
    const unsigned fld = (r & 1) ? sHi : sLo;
    const unsigned cnt = (r & 2) ? (fld >> 16) : (fld & 0xFFFFu);

    if (lane < NREG) {
        const float nz = (float)max(ez - sz, 0);
        const float ny = (float)max(ey - sy, 0);
        const float nx = (float)max(ex - sx, 0);
        const float denom = fmaxf(nz * ny * nx, 1.0f);
        const float s = (float)tot / denom + (float)NREG * 1e-6f;
        const float a = (float)cnt / denom + 1e-6f;
        out[RF_N + patch * NREG + lane] = a / s;
    }
}

// ---------------------------------------------------------------------------
extern "C" void kernel_launch(void* const* d_in, const int* in_sizes, int n_in,
                              void* d_out, int out_size, void* d_ws, size_t ws_size,
                              hipStream_t stream)
{
    const int*   seg    = (const int*)d_in[0];
    const float* coords = (const float*)d_in[1];
    const float* proto  = (const float*)d_in[2];
    float*       out    = (float*)d_out;
    unsigned*    ws     = (unsigned*)d_ws;

    hipMemsetAsync(ws + W_COUNTS, 0, NBUCKET * sizeof(unsigned), stream);
    hipLaunchKernelGGL(count_kernel, dim3(TOTAL_PATCHES / 256), dim3(256),
                       0, stream, coords, proto, out, ws);
    hipLaunchKernelGGL(scan_kernel, dim3(1), dim3(NBUCKET), 0, stream, ws);
    hipLaunchKernelGGL(scatter_kernel, dim3(TOTAL_PATCHES / 256), dim3(256),
                       0, stream, coords, ws);
    hipLaunchKernelGGL(fused_kernel, dim3(FUSED_BLOCKS), dim3(256),
                       0, stream, seg, ws, out);
}

// Round 12
// 52.595 us; speedup vs baseline: 7.8156x; 7.8156x over previous
//
#include <hip/hip_runtime.h>
#include <stdint.h>

#define NREG   20
#define EDIM   768
#define DVOL   64
#define HVOL   512
#define WVOL   512
#define HW_    (HVOL * WVOL)
#define DHW_   (DVOL * HVOL * WVOL)
#define NPATCH 16384
#define BTOT   2
#define PROTO_N (NREG * EDIM)            // 15360
#define RF_N    (BTOT * PROTO_N)         // 30720 floats (output 0)
#define TOTAL_PATCHES (BTOT * NPATCH)    // 32768
#define NBUCKET 1024                     // 2 b x 32 zbins x 16 ybins
#define SORT_BLOCKS 8                    // co-resident by capacity -> safe spin

// workspace layout (u32 words)
#define W_PHASE 0                        // 1 word (zeroed by memset each launch)
#define W_BCNT  32                       // 8 x 1024 per-block bucket counts
#define W_PID   (W_BCNT + SORT_BLOCKS * NBUCKET)
#define W_C0    (W_PID  + TOTAL_PATCHES)
#define W_C1    (W_C0   + TOTAL_PATCHES)
#define W_C2    (W_C1   + TOTAL_PATCHES)
#define MEMSET_WORDS (W_BCNT + SORT_BLOCKS * NBUCKET)

// 16-byte load with only 4-byte alignment guarantee.
struct __attribute__((packed, aligned(4))) int4p { int x, y, z, w; };

// ---------------------------------------------------------------------------
// Single-dispatch global counting sort. 8 blocks x 1024 threads; each block
// owns 4096 consecutive patches. Phases:
//   1) LDS histogram of own keys -> plain-store to bcnt[blk][*]
//   2) release phase++ ; spin (acquire) until all 8 counted
//   3) every block redundantly: totals + exclusive scan + own base cursor
//   4) scatter own patches via LDS cursor atomics (pid + SoA coords)
// 8 blocks are co-resident by capacity -> the spin cannot deadlock.
// ---------------------------------------------------------------------------
__global__ __launch_bounds__(1024) void sort_kernel(
    const float* __restrict__ coords, unsigned* __restrict__ ws)
{
    __shared__ unsigned lcnt[NBUCKET];    // histogram, then scan workspace
    __shared__ unsigned lofs[NBUCKET];    // block's scatter cursors

    float* wsf = (float*)ws;
    const int blk = (int)blockIdx.x;      // 0..7
    const int t   = (int)threadIdx.x;     // 0..1023
    const int p0  = blk * 4096 + t * 4;   // 4 consecutive patches per thread
    const int b   = blk >> 2;             // batch (uniform per block)

    lcnt[t] = 0u;
    __syncthreads();

    // 4 patches: 12 contiguous floats, 16B-aligned (48B stride)
    float c[12];
    {
        const float4* cp = (const float4*)(coords + (size_t)p0 * 3);
        const float4 a = cp[0], bb = cp[1], d = cp[2];
        c[0]=a.x;  c[1]=a.y;  c[2]=a.z;  c[3]=a.w;  c[4]=bb.x; c[5]=bb.y;
        c[6]=bb.z; c[7]=bb.w; c[8]=d.x;  c[9]=d.y;  c[10]=d.z; c[11]=d.w;
    }
    unsigned key[4];
#pragma unroll
    for (int i = 0; i < 4; ++i) {
        const int zbin = ((int)(c[3*i + 0] * 64.0f))  >> 1;   // 0..31
        const int ybin = ((int)(c[3*i + 1] * 512.0f)) >> 5;   // 0..15
        key[i] = (unsigned)(b * 512 + zbin * 16 + ybin);
        atomicAdd(&lcnt[key[i]], 1u);
    }
    __syncthreads();

    ws[W_BCNT + blk * NBUCKET + t] = lcnt[t];     // plain store (release below)
    __syncthreads();

    if (t == 0) {
        __hip_atomic_fetch_add(&ws[W_PHASE], 1u,
                               __ATOMIC_RELEASE, __HIP_MEMORY_SCOPE_AGENT);
        int guard = 0;
        while (__hip_atomic_load(&ws[W_PHASE],
                 __ATOMIC_ACQUIRE, __HIP_MEMORY_SCOPE_AGENT) < SORT_BLOCKS
               && guard < (1 << 22)) {
            __builtin_amdgcn_s_sleep(1);
            ++guard;
        }
    }
    __syncthreads();

    // totals + this block's "before" share for bucket t
    unsigned tot = 0u, before = 0u;
#pragma unroll
    for (int k = 0; k < SORT_BLOCKS; ++k) {
        const unsigned v = ws[W_BCNT + k * NBUCKET + t];
        tot += v;
        before += (k < blk) ? v : 0u;
    }
    lcnt[t] = tot;
    __syncthreads();

    // inclusive scan over 1024 buckets
#pragma unroll
    for (int off = 1; off < NBUCKET; off <<= 1) {
        const unsigned u = (t >= off) ? lcnt[t - off] : 0u;
        __syncthreads();
        lcnt[t] += u;
        __syncthreads();
    }
    lofs[t] = (lcnt[t] - tot) + before;           // exclusive prefix + base
    __syncthreads();

    // scatter own 4 patches
#pragma unroll
    for (int i = 0; i < 4; ++i) {
        const unsigned rank = atomicAdd(&lofs[key[i]], 1u);
        ws[W_PID + rank] = (unsigned)(p0 + i);
        wsf[W_C0 + rank] = c[3*i + 0];
        wsf[W_C1 + rank] = c[3*i + 1];
        wsf[W_C2 + rank] = c[3*i + 2];
    }
}

// ---------------------------------------------------------------------------
// Assign (unchanged from R10, proven): one wave per globally-sorted slot,
// XCD swizzle -> each XCD sweeps a contiguous spatial slice. 4 unconditional
// int4 gathers, packed 8-bit histogram, shfl butterfly, in-register finish.
// Blocks 0..119 also copy the prototype broadcast (output 0).
// ---------------------------------------------------------------------------
__global__ __launch_bounds__(256) void assign_kernel(
    const int*      __restrict__ seg,
    const unsigned* __restrict__ ws,
    const float*    __restrict__ proto,
    float*          __restrict__ out)
{
    if (blockIdx.x < RF_N / 256) {
        const int i = (int)blockIdx.x * 256 + (int)threadIdx.x;
        out[i] = proto[i >= PROTO_N ? i - PROTO_N : i];
    }

    const int bid  = (int)blockIdx.x;
    const int sbid = (bid & 7) * 1024 + (bid >> 3);

    const int lane = threadIdx.x & 63;
    const int wave = threadIdx.x >> 6;
    const int slot = sbid * 4 + wave;

    const int   patch = (int)ws[W_PID + slot];                  // uniform
    const float c0 = ((const float*)ws)[W_C0 + slot] * 64.0f;   // z
    const float c1 = ((const float*)ws)[W_C1 + slot] * 512.0f;  // y
    const float c2 = ((const float*)ws)[W_C2 + slot] * 512.0f;  // x
    const int b = patch >> 14;

    const int sz = (int)fmaxf(0.0f,   floorf(c0 - 2.0f));
    const int ez = (int)fminf(64.0f,  floorf(c0 + 2.0f));
    const int sy = (int)fmaxf(0.0f,   floorf(c1 - 8.0f));
    const int ey = (int)fminf(512.0f, floorf(c1 + 8.0f));
    const int sx = (int)fmaxf(0.0f,   floorf(c2 - 8.0f));
    const int ex = (int)fminf(512.0f, floorf(c2 + 8.0f));

    const int xl4  = lane & 3;
    const int yy   = lane >> 2;
    const int p_lo = sx + 4 * xl4;
    const int st   = min(p_lo, WVOL - 4);
    const int yi   = sy + yy;
    const unsigned vy = (yi < ey) ? 0xFFFFFFFFu : 0u;
    const int yiC  = min(yi, HVOL - 1);
    const int rowbase = b * DHW_ + yiC * WVOL + st;

    unsigned vm[4];
#pragma unroll
    for (int j = 0; j < 4; ++j) {
        const int pos = st + j;
        vm[j] = (pos >= p_lo && pos < ex) ? vy : 0u;
    }

    int4p q0, q1, q2, q3;
    {
        const int z0 = min(sz + 0, DVOL - 1) * HW_;
        const int z1 = min(sz + 1, DVOL - 1) * HW_;
        const int z2 = min(sz + 2, DVOL - 1) * HW_;
        const int z3 = min(sz + 3, DVOL - 1) * HW_;
        q0 = *(const int4p*)(seg + rowbase + z0);
        q1 = *(const int4p*)(seg + rowbase + z1);
        q2 = *(const int4p*)(seg + rowbase + z2);
        q3 = *(const int4p*)(seg + rowbase + z3);
    }

    unsigned cc[5] = {0u, 0u, 0u, 0u, 0u};
#pragma unroll
    for (int z = 0; z < 4; ++z) {
        const unsigned zm = (sz + z < ez) ? 0xFFFFFFFFu : 0u;
        const int4p qz = (z == 0) ? q0 : (z == 1) ? q1 : (z == 2) ? q2 : q3;
        const int vals[4] = {qz.x, qz.y, qz.z, qz.w};
#pragma unroll
        for (int j = 0; j < 4; ++j) {
            const int v = vals[j] & (int)(vm[j] & zm);   // invalid -> 0
            const int t = v - 1;                         // -1 if not counted
            const unsigned inc = 1u << ((t & 3) << 3);
            const int qk = t >> 2;                       // -1 matches no k
#pragma unroll
            for (int k = 0; k < 5; ++k)
                cc[k] += (qk == k) ? inc : 0u;
        }
    }

#pragma unroll
    for (int off = 1; off < 8; off <<= 1) {
#pragma unroll
        for (int k = 0; k < 5; ++k)
            cc[k] += (unsigned)__shfl_xor((int)cc[k], off);
    }

    unsigned lo[5], hi[5];
#pragma unroll
    for (int k = 0; k < 5; ++k) {
        lo[k] = cc[k] & 0x00FF00FFu;          // regions 4k (lo16), 4k+2 (hi16)
        hi[k] = (cc[k] >> 8) & 0x00FF00FFu;   // regions 4k+1,      4k+3
    }
#pragma unroll
    for (int off = 8; off < 64; off <<= 1) {
#pragma unroll
        for (int k = 0; k < 5; ++k) {
            lo[k] += (unsigned)__shfl_xor((int)lo[k], off);
            hi[k] += (unsigned)__shfl_xor((int)hi[k], off);
        }
    }

    unsigned S = 0u;
#pragma unroll
    for (int k = 0; k < 5; ++k) S += lo[k] + hi[k];
    const unsigned tot = (S & 0xFFFFu) + (S >> 16);   // <= 1024, no carry

    const int r = lane & 3;
    const unsigned sLo = (lane < 4) ? lo[0] : (lane < 8) ? lo[1]
                       : (lane < 12) ? lo[2] : (lane < 16) ? lo[3] : lo[4];
    const unsigned sHi = (lane < 4) ? hi[0] : (lane < 8) ? hi[1]
                       : (lane < 12) ? hi[2] : (lane < 16) ? hi[3] : hi[4];
    const unsigned fld = (r & 1) ? sHi : sLo;
    const unsigned cnt = (r & 2) ? (fld >> 16) : (fld & 0xFFFFu);

    if (lane < NREG) {
        const float nz = (float)max(ez - sz, 0);
        const float ny = (float)max(ey - sy, 0);
        const float nx = (float)max(ex - sx, 0);
        const float denom = fmaxf(nz * ny * nx, 1.0f);
        const float s = (float)tot / denom + (float)NREG * 1e-6f;
        const float a = (float)cnt / denom + 1e-6f;
        out[RF_N + patch * NREG + lane] = a / s;
    }
}

// ---------------------------------------------------------------------------
extern "C" void kernel_launch(void* const* d_in, const int* in_sizes, int n_in,
                              void* d_out, int out_size, void* d_ws, size_t ws_size,
                              hipStream_t stream)
{
    const int*   seg    = (const int*)d_in[0];
    const float* coords = (const float*)d_in[1];
    const float* proto  = (const float*)d_in[2];
    float*       out    = (float*)d_out;
    unsigned*    ws     = (unsigned*)d_ws;

    hipMemsetAsync(ws, 0, MEMSET_WORDS * sizeof(unsigned), stream);
    hipLaunchKernelGGL(sort_kernel, dim3(SORT_BLOCKS), dim3(1024),
                       0, stream, coords, ws);
    hipLaunchKernelGGL(assign_kernel, dim3(TOTAL_PATCHES / 4), dim3(256),
                       0, stream, seg, ws, proto, out);
}